// Round 9
// baseline (656.225 us; speedup 1.0000x reference)
//
#include <hip/hip_runtime.h>
#include <cstdint>
#include <cstddef>

// ---------------------------------------------------------------------------
// JambaMambaBlock on MI355X (gfx950)
// Pipeline: rmsnorm -> GEMM1(in_proj, split epilogue: x fp32 / silu(z) bf16)
//           -> depthwise conv+silu -> GEMM2(x_proj, softplus epilogue)
//           -> chunked SSM scan (3 phases) -> GEMM3(out_proj, +residual)
//
// GEMMs (round 9): barrier-free direct-global K-loop, mfma_32x32x16_bf16,
// 128-thr blocks (2 waves), block tile 128x128, wave tile 64x128.
// Operands pre-swizzled into 32-row x 16-k fragment tiles (1 KB):
//   elem(row,k) -> tile=(row>>5)*128+(k>>4), lane=(row&31)+32*((k>>3)&1), j=k&7
// Depth-2 register pipeline: 6 frags/slot (24 VGPR) -> ~200 VGPR total,
// no spill under __launch_bounds__(128,2) (round 8's 16x16 shape needed
// 96 frag regs and spilled ~100 MB of scratch per launch).
// CU operand demand at full MFMA = 4060*(1/64+1/128) = 95 B/cyc < L1 port.
// Scan: 32 chunks of 64 steps; 4 lanes per d-channel; depth-4 reg prefetch.
// ---------------------------------------------------------------------------

typedef __bf16 bf16_t;
typedef __attribute__((ext_vector_type(8))) __bf16 bf16x8;
typedef __attribute__((ext_vector_type(4))) __bf16 bf16x4;
typedef __attribute__((ext_vector_type(4))) float f32x4;
typedef __attribute__((ext_vector_type(16))) float f32x16;

#define D_MODEL 2048
#define D_STATE 16
#define B_SZ 2
#define T_LEN 2048
#define N_ROWS (B_SZ * T_LEN)        // 4096
#define N_PAD 2176                   // x_proj rows padded 2080 -> 17*128
#define P_PITCH 2176                 // PROJ row pitch
#define N_CHUNK 32
#define L_CHUNK (T_LEN / N_CHUNK)    // 64
#define LOG2E 1.4426950408889634f
#define KT2 128                      // K=2048 -> 128 k-tiles of 16
#define PANEL2 65536                 // elems per 32-row panel (128 tiles*512)

// ---------------- fused weight cast + swizzle ----------------
// one wave per 1KB tile. W1 16384 | W2 8704 (rows>=2080 zero) | W3 8192
__global__ __launch_bounds__(256) void cast_weights(
    const float* __restrict__ w_in, const float* __restrict__ w_x,
    const float* __restrict__ w_out,
    bf16_t* __restrict__ W1s, bf16_t* __restrict__ W2s, bf16_t* __restrict__ W3s)
{
    int wv   = blockIdx.x * 4 + (threadIdx.x >> 6);
    int lane = threadIdx.x & 63;
    const float* src; bf16_t* dst; int nrows; int tile;
    if (wv < 16384)      { src = w_in;  dst = W1s; tile = wv;         nrows = 4096; }
    else if (wv < 25088) { src = w_x;   dst = W2s; tile = wv - 16384; nrows = 2080; }
    else                 { src = w_out; dst = W3s; tile = wv - 25088; nrows = 2048; }
    int r32 = tile >> 7, kt = tile & 127;
    int row = r32 * 32 + (lane & 31);
    int k0  = kt * 16 + (lane >> 5) * 8;
    f32x4 v0 = {0.f, 0.f, 0.f, 0.f}, v1 = v0;
    if (row < nrows) {
        v0 = *(const f32x4*)&src[(size_t)row * 2048 + k0];
        v1 = *(const f32x4*)&src[(size_t)row * 2048 + k0 + 4];
    }
    bf16x4 lo = __builtin_convertvector(v0, bf16x4);
    bf16x4 hi = __builtin_convertvector(v1, bf16x4);
    bf16x8 o;
    #pragma unroll
    for (int e = 0; e < 4; ++e) { o[e] = lo[e]; o[e + 4] = hi[e]; }
    *(bf16x8*)(dst + (size_t)tile * 512 + lane * 8) = o;
}

// ---------------- rmsnorm -> swizzled bf16 ----------------
// one block per 32-row panel. Phase A: coalesced read + per-row scale.
// Phase B: output-driven swizzled stores (re-reads x from L2-hot panel).
__global__ __launch_bounds__(256) void rmsnorm_swz(
    const float* __restrict__ x, const float* __restrict__ w,
    bf16_t* __restrict__ xn)
{
    __shared__ float sc[32];
    int r32 = blockIdx.x;            // 0..127
    int tid = threadIdx.x;
    int wave = tid >> 6, lane = tid & 63;

    #pragma unroll
    for (int rr = 0; rr < 8; ++rr) {
        int row = r32 * 32 + wave * 8 + rr;
        const float* xr = x + (size_t)row * 2048;
        float ss = 0.f;
        #pragma unroll
        for (int c = 0; c < 8; ++c) {
            f32x4 v = *(const f32x4*)&xr[(c * 64 + lane) * 4];
            ss += v[0]*v[0] + v[1]*v[1] + v[2]*v[2] + v[3]*v[3];
        }
        #pragma unroll
        for (int o = 32; o > 0; o >>= 1) ss += __shfl_down(ss, o, 64);
        if (lane == 0) sc[wave * 8 + rr] = rsqrtf(ss * (1.f / 2048.f) + 1e-6f);
    }
    __syncthreads();

    const size_t base = (size_t)r32 * PANEL2;
    #pragma unroll
    for (int c = 0; c < 32; ++c) {
        int f    = (c * 256 + tid) * 8;      // swizzled flat element offset
        int tile = f >> 9;                   // kt 0..127
        int li   = (f >> 3) & 63;
        int rowl = li & 31;
        int k    = tile * 16 + (li >> 5) * 8;
        int row  = r32 * 32 + rowl;
        f32x4 v0 = *(const f32x4*)&x[(size_t)row * 2048 + k];
        f32x4 v1 = *(const f32x4*)&x[(size_t)row * 2048 + k + 4];
        f32x4 w0 = *(const f32x4*)&w[k];
        f32x4 w1 = *(const f32x4*)&w[k + 4];
        float s = sc[rowl];
        bf16x8 o;
        #pragma unroll
        for (int e = 0; e < 4; ++e) {
            o[e]     = (bf16_t)(v0[e] * s * w0[e]);
            o[e + 4] = (bf16_t)(v1[e] * s * w1[e]);
        }
        *(bf16x8*)(xn + base + f) = o;
    }
}

// ---------------- bf16 GEMM: C[M,N] = A @ B^T, 32x32x16 fragment-direct ---
// 128 threads = 2 waves (M halves); block tile 128x128; wave tile 64x128.
// MODE 0 (GEMM1): bn<16 -> out0 fp32 ldc 2048; bn>=16 -> out1 bf16 silu
// MODE 1 (GEMM2): out0 fp32 ldc P_PITCH; softplus when bn<16
// MODE 2 (GEMM3): out0 = v + add, fp32 ldc 2048
template<int MODE>
__global__ __launch_bounds__(128, 2) void gemm_bt(
    const bf16_t* __restrict__ A, const bf16_t* __restrict__ B,
    float* __restrict__ out0, bf16_t* __restrict__ out1,
    const float* __restrict__ add)
{
    __shared__ __align__(16) float cs[2][32 * 132];   // per-wave epilogue strip
    const int tid = threadIdx.x;
    const int bm = blockIdx.x, bn = blockIdx.y;
    const int lane = tid & 63;
    const int wave = tid >> 6;

    const bf16_t* A0 = A + (((size_t)(bm * 4 + wave * 2)) << 16) + lane * 8;
    const bf16_t* A1 = A0 + PANEL2;
    const bf16_t* B0 = B + (((size_t)bn * 4) << 16) + lane * 8;

    f32x16 acc[2][4];
    #pragma unroll
    for (int i = 0; i < 2; ++i)
        #pragma unroll
        for (int j = 0; j < 4; ++j)
            #pragma unroll
            for (int r = 0; r < 16; ++r) acc[i][j][r] = 0.f;

    bf16x8 aF[2][2], bF[2][4];
    #pragma unroll
    for (int s = 0; s < 2; ++s) {
        aF[s][0] = *(const bf16x8*)(A0 + s * 512);
        aF[s][1] = *(const bf16x8*)(A1 + s * 512);
        #pragma unroll
        for (int j = 0; j < 4; ++j)
            bF[s][j] = *(const bf16x8*)(B0 + (size_t)j * PANEL2 + s * 512);
    }

    for (int kt = 0; kt < KT2; kt += 2) {
        // slot 0: compute kt, refill with kt+2
        #pragma unroll
        for (int j = 0; j < 4; ++j) {
            acc[0][j] = __builtin_amdgcn_mfma_f32_32x32x16_bf16(
                aF[0][0], bF[0][j], acc[0][j], 0, 0, 0);
            acc[1][j] = __builtin_amdgcn_mfma_f32_32x32x16_bf16(
                aF[0][1], bF[0][j], acc[1][j], 0, 0, 0);
        }
        {
            int ktn = kt + 2; if (ktn > KT2 - 1) ktn = KT2 - 1;
            size_t off = (size_t)ktn << 9;
            aF[0][0] = *(const bf16x8*)(A0 + off);
            aF[0][1] = *(const bf16x8*)(A1 + off);
            #pragma unroll
            for (int j = 0; j < 4; ++j)
                bF[0][j] = *(const bf16x8*)(B0 + (size_t)j * PANEL2 + off);
        }
        // slot 1: compute kt+1, refill with kt+3
        #pragma unroll
        for (int j = 0; j < 4; ++j) {
            acc[0][j] = __builtin_amdgcn_mfma_f32_32x32x16_bf16(
                aF[1][0], bF[1][j], acc[0][j], 0, 0, 0);
            acc[1][j] = __builtin_amdgcn_mfma_f32_32x32x16_bf16(
                aF[1][1], bF[1][j], acc[1][j], 0, 0, 0);
        }
        {
            int ktn = kt + 3; if (ktn > KT2 - 1) ktn = KT2 - 1;
            size_t off = (size_t)ktn << 9;
            aF[1][0] = *(const bf16x8*)(A0 + off);
            aF[1][1] = *(const bf16x8*)(A1 + off);
            #pragma unroll
            for (int j = 0; j < 4; ++j)
                bF[1][j] = *(const bf16x8*)(B0 + (size_t)j * PANEL2 + off);
        }
    }

    // ---- per-wave LDS strip epilogue ----
    // 32x32 C/D layout (verified m74/m101): col = lane&31,
    // row = (r&3) + 8*(r>>2) + 4*(lane>>5)
    const int cl = lane & 31;
    const int rh = (lane >> 5) * 4;
    float* csw = cs[wave];
    for (int i = 0; i < 2; ++i) {              // two 32-row strips
        #pragma unroll
        for (int j = 0; j < 4; ++j)
            #pragma unroll
            for (int r = 0; r < 16; ++r)
                csw[((r & 3) + 8 * (r >> 2) + rh) * 132 + j * 32 + cl] = acc[i][j][r];
        #pragma unroll
        for (int s = 0; s < 16; ++s) {
            int t    = lane + s * 64;          // 0..1023 f32x4 chunks
            int rowl = t >> 5;                 // 0..31
            int c4   = (t & 31) * 4;
            f32x4 v = *(const f32x4*)&csw[rowl * 132 + c4];
            int gr = bm * 128 + wave * 64 + i * 32 + rowl;
            int gc = bn * 128 + c4;
            if (MODE == 0) {
                if (bn < 16) {
                    *(f32x4*)&out0[(size_t)gr * 2048 + gc] = v;
                } else {
                    bf16x4 o;
                    #pragma unroll
                    for (int e = 0; e < 4; ++e) {
                        float sv = v[e];
                        o[e] = (bf16_t)(sv / (1.f + __expf(-sv)));
                    }
                    *(bf16x4*)&out1[(size_t)gr * 2048 + (gc - 2048)] = o;
                }
            } else if (MODE == 1) {
                if (bn < 16) {
                    #pragma unroll
                    for (int e = 0; e < 4; ++e) {
                        float sv = v[e];
                        v[e] = fmaxf(sv, 0.f) + __logf(1.f + __expf(-fabsf(sv)));
                    }
                }
                *(f32x4*)&out0[(size_t)gr * P_PITCH + gc] = v;
            } else {
                f32x4 a4 = *(const f32x4*)&add[(size_t)gr * 2048 + gc];
                v = v + a4;
                *(f32x4*)&out0[(size_t)gr * 2048 + gc] = v;
            }
        }
    }
}

// ---------------- depthwise causal conv(4) + silu -> swizzled bf16 --------
// wave-per-tile: one 1KB tile (32 t-rows x 16 d) per wave, coalesced store.
__global__ __launch_bounds__(256) void conv_silu_swz(
    const float* __restrict__ xb, const float* __restrict__ cw,
    const float* __restrict__ cb, bf16_t* __restrict__ xs_s)
{
    int tile = blockIdx.x * 4 + (threadIdx.x >> 6);   // 0..16383
    int lane = threadIdx.x & 63;
    int r32  = tile >> 7;                // 32-row group (0..127)
    int kt   = tile & 127;               // d-tile
    int d0   = kt * 16 + (lane >> 5) * 8;
    int row  = r32 * 32 + (lane & 31);
    int t    = row & 2047;               // t within batch

    float a[8];
    {
        f32x4 b0 = *(const f32x4*)&cb[d0], b1 = *(const f32x4*)&cb[d0 + 4];
        #pragma unroll
        for (int e = 0; e < 4; ++e) { a[e] = b0[e]; a[4 + e] = b1[e]; }
    }
    f32x4 cwv[8];
    #pragma unroll
    for (int e = 0; e < 8; ++e) cwv[e] = *(const f32x4*)&cw[(d0 + e) * 4];

    #pragma unroll
    for (int tap = 0; tap < 4; ++tap) {
        int tr = t - 3 + tap;
        if (tr >= 0) {
            const float* xr = xb + ((size_t)(row - 3 + tap)) * 2048 + d0;
            f32x4 x0 = *(const f32x4*)xr, x1 = *(const f32x4*)(xr + 4);
            #pragma unroll
            for (int e = 0; e < 4; ++e) {
                a[e]     = fmaf(cwv[e][tap],     x0[e], a[e]);
                a[4 + e] = fmaf(cwv[4 + e][tap], x1[e], a[4 + e]);
            }
        }
    }
    bf16x8 o;
    #pragma unroll
    for (int e = 0; e < 8; ++e) {
        float s = a[e];
        o[e] = (bf16_t)(s / (1.f + __expf(-s)));
    }
    *(bf16x8*)(xs_s + (size_t)tile * 512 + lane * 8) = o;
}

// ---------------- chunked SSM scan ----------------
// Wave wi in [0,8192): c = wi&31, dg = (wi>>5)&127, b = wi>>12.
// Lane: nq = lane&3 (state quad), dsub = lane>>2; dd = dg*16 + dsub.
// xs/yg fragment-swizzled bf16 (32-row tiles); proj row-major fp32 pitch 2176.
#define PF 4   // prefetch depth

__device__ __forceinline__ size_t xs_off(int row, int ddo) {
    return ((size_t)(row >> 5) << 16) + (size_t)((row & 31) << 3) + ddo;
}

// phase 1: local scan with zero init; store decay product + local final state
__global__ __launch_bounds__(256) void scan_phase1(
    const float* __restrict__ proj, const bf16_t* __restrict__ xs,
    const float* __restrict__ A_log,
    float* __restrict__ Aprod, float* __restrict__ hfin)
{
    int wi   = blockIdx.x * 4 + (threadIdx.x >> 6);
    int lane = threadIdx.x & 63;
    int nq   = lane & 3;
    int dsub = lane >> 2;
    int c  = wi & 31;
    int dg = (wi >> 5) & 127;
    int b  = wi >> 12;
    int dd = dg * 16 + dsub;
    const int ddo = ((dd >> 4) << 9) + (((dd >> 3) & 1) << 8) + (dd & 7);

    float A2[4], h[4], Ap[4];
    #pragma unroll
    for (int j = 0; j < 4; ++j) {
        A2[j] = -__expf(A_log[dd * D_STATE + nq * 4 + j]) * LOG2E;
        h[j] = 0.f; Ap[j] = 1.f;
    }
    const int t0 = c * L_CHUNK;
    const int tmax = t0 + L_CHUNK - 1;

    float p_da[PF], p_xv[PF];
    f32x4 p_B[PF];
    #pragma unroll
    for (int u = 0; u < PF; ++u) {
        int row = b * T_LEN + t0 + u;
        const float* pr = proj + (size_t)row * P_PITCH;
        p_da[u] = pr[dd];
        p_xv[u] = (float)xs[xs_off(row, ddo)];
        p_B[u]  = *(const f32x4*)(pr + D_MODEL + nq * 4);
    }

    for (int it = 0; it < L_CHUNK; it += PF) {
        #pragma unroll
        for (int u = 0; u < PF; ++u) {
            int t = t0 + it + u;
            float da = p_da[u], xv = p_xv[u];
            f32x4 Bv = p_B[u];
            int tn = t + PF; tn = (tn > tmax) ? tmax : tn;
            {
                int row = b * T_LEN + tn;
                const float* pr = proj + (size_t)row * P_PITCH;
                p_da[u] = pr[dd];
                p_xv[u] = (float)xs[xs_off(row, ddo)];
                p_B[u]  = *(const f32x4*)(pr + D_MODEL + nq * 4);
            }
            float dx = da * xv;
            #pragma unroll
            for (int j = 0; j < 4; ++j) {
                float a = exp2f(da * A2[j]);
                Ap[j] *= a;
                h[j] = fmaf(a, h[j], dx * Bv[j]);
            }
        }
    }
    size_t o = ((size_t)c * 4096 + b * 2048 + dd) * D_STATE + nq * 4;
    *(f32x4*)(Aprod + o) = f32x4{Ap[0], Ap[1], Ap[2], Ap[3]};
    *(f32x4*)(hfin  + o) = f32x4{h[0], h[1], h[2], h[3]};
}

// phase 2: serial combine across chunks; hfin -> h_init in place; h_out exact
__global__ __launch_bounds__(256) void scan_phase2(
    const float* __restrict__ h_in, const float* __restrict__ Aprod,
    float* __restrict__ hfin, float* __restrict__ h_out)
{
    int g = blockIdx.x * 256 + threadIdx.x;
    float h = h_in[g];
    for (int c = 0; c < N_CHUNK; ++c) {
        size_t o = (size_t)c * 65536 + g;
        float a   = Aprod[o];
        float loc = hfin[o];
        hfin[o] = h;
        h = fmaf(a, h, loc);
    }
    h_out[g] = h;
}

// phase 3: replay from exact initial state; emit gated y (swizzled bf16)
__global__ __launch_bounds__(256) void scan_phase3(
    const float* __restrict__ proj, const bf16_t* __restrict__ xs,
    const bf16_t* __restrict__ zg, const float* __restrict__ A_log,
    const float* __restrict__ Dv, const float* __restrict__ hinit,
    bf16_t* __restrict__ yg)
{
    int wi   = blockIdx.x * 4 + (threadIdx.x >> 6);
    int lane = threadIdx.x & 63;
    int nq   = lane & 3;
    int dsub = lane >> 2;
    int c  = wi & 31;
    int dg = (wi >> 5) & 127;
    int b  = wi >> 12;
    int dd = dg * 16 + dsub;
    const int ddo = ((dd >> 4) << 9) + (((dd >> 3) & 1) << 8) + (dd & 7);

    float A2[4], h[4];
    size_t o = ((size_t)c * 4096 + b * 2048 + dd) * D_STATE + nq * 4;
    #pragma unroll
    for (int j = 0; j < 4; ++j) {
        A2[j] = -__expf(A_log[dd * D_STATE + nq * 4 + j]) * LOG2E;
        h[j]  = hinit[o + j];
    }
    float Dd = Dv[dd];
    const int t0 = c * L_CHUNK;
    const int tmax = t0 + L_CHUNK - 1;

    float p_da[PF], p_xv[PF], p_sz[PF];
    f32x4 p_B[PF], p_C[PF];
    #pragma unroll
    for (int u = 0; u < PF; ++u) {
        int row = b * T_LEN + t0 + u;
        const float* pr = proj + (size_t)row * P_PITCH;
        p_da[u] = pr[dd];
        p_xv[u] = (float)xs[xs_off(row, ddo)];
        p_sz[u] = (float)zg[(size_t)row * 2048 + dd];
        p_B[u]  = *(const f32x4*)(pr + D_MODEL + nq * 4);
        p_C[u]  = *(const f32x4*)(pr + D_MODEL + D_STATE + nq * 4);
    }

    for (int it = 0; it < L_CHUNK; it += PF) {
        #pragma unroll
        for (int u = 0; u < PF; ++u) {
            int t = t0 + it + u;
            float da = p_da[u], xv = p_xv[u], sz = p_sz[u];
            f32x4 Bv = p_B[u], Cv = p_C[u];
            int tn = t + PF; tn = (tn > tmax) ? tmax : tn;
            {
                int row = b * T_LEN + tn;
                const float* pr = proj + (size_t)row * P_PITCH;
                p_da[u] = pr[dd];
                p_xv[u] = (float)xs[xs_off(row, ddo)];
                p_sz[u] = (float)zg[(size_t)row * 2048 + dd];
                p_B[u]  = *(const f32x4*)(pr + D_MODEL + nq * 4);
                p_C[u]  = *(const f32x4*)(pr + D_MODEL + D_STATE + nq * 4);
            }
            float dx = da * xv;
            float yp = 0.f;
            #pragma unroll
            for (int j = 0; j < 4; ++j) {
                float a = exp2f(da * A2[j]);
                h[j] = fmaf(a, h[j], dx * Bv[j]);
                yp = fmaf(h[j], Cv[j], yp);
            }
            yp += __shfl_xor(yp, 1, 64);
            yp += __shfl_xor(yp, 2, 64);
            if (nq == 0) {
                float y = fmaf(Dd, xv, yp);
                int row = b * T_LEN + t;
                yg[xs_off(row, ddo)] = (bf16_t)(y * sz);
            }
        }
    }
}

// ---------------------------------------------------------------------------
extern "C" void kernel_launch(void* const* d_in, const int* in_sizes, int n_in,
                              void* d_out, int out_size, void* d_ws, size_t ws_size,
                              hipStream_t stream)
{
    const float* x    = (const float*)d_in[0];
    const float* h0   = (const float*)d_in[1];
    const float* nw   = (const float*)d_in[2];
    const float* w_in = (const float*)d_in[3];
    const float* cw   = (const float*)d_in[4];
    const float* cb   = (const float*)d_in[5];
    const float* w_x  = (const float*)d_in[6];
    const float* alog = (const float*)d_in[7];
    const float* dv   = (const float*)d_in[8];
    const float* w_out= (const float*)d_in[9];
    float* out  = (float*)d_out;
    float* hout = out + (size_t)N_ROWS * D_MODEL;

    char* ws = (char*)d_ws;
    size_t off = 0;
    auto alloc = [&](size_t bytes) -> void* {
        void* p = ws + off;
        off += (bytes + 255) & ~(size_t)255;
        return p;
    };
    bf16_t* W1  = (bf16_t*)alloc((size_t)16384 * 512 * 2);   // in_proj swizzled
    bf16_t* W2  = (bf16_t*)alloc((size_t)8704 * 512 * 2);    // x_proj swizzled+pad
    bf16_t* W3  = (bf16_t*)alloc((size_t)8192 * 512 * 2);    // out_proj swizzled
    bf16_t* XN  = (bf16_t*)alloc((size_t)N_ROWS * 2048 * 2); // normed x, swizzled
    float*  XB  = (float*) alloc((size_t)N_ROWS * 2048 * 4); // x-branch fp32 rm
    bf16_t* ZG  = (bf16_t*)alloc((size_t)N_ROWS * 2048 * 2); // silu(z) bf16 rm
    float*  PROJ= (float*) alloc((size_t)N_ROWS * P_PITCH * 4);// da|B|C fp32 rm
    float* APROD= (float*) alloc((size_t)N_CHUNK * 4096 * D_STATE * 4);
    float* HFIN = (float*) alloc((size_t)N_CHUNK * 4096 * D_STATE * 4);
    // aliases (lifetimes disjoint in stream order):
    bf16_t* XSb = W1;   // conv out, swizzled (W1 dead after GEMM1; lives thru scan)
    bf16_t* YG  = XN;   // gated y, swizzled  (XN dead after GEMM1)

    // weight casts + swizzle (33280 tiles, 4 waves/block)
    cast_weights<<<8320, 256, 0, stream>>>(w_in, w_x, w_out, W1, W2, W3);

    // 1) rmsnorm -> swizzled XN
    rmsnorm_swz<<<128, 256, 0, stream>>>(x, nw, XN);
    // 2) xz = xn @ W_in^T; epilogue splits x fp32 / silu(z) bf16
    gemm_bt<0><<<dim3(32, 32), 128, 0, stream>>>(XN, W1, XB, ZG, nullptr);
    // 3) conv + silu -> swizzled bf16 (wave-per-tile, coalesced stores)
    conv_silu_swz<<<4096, 256, 0, stream>>>(XB, cw, cb, XSb);
    // 4) proj = xssm @ W_x^T; epilogue applies softplus to delta cols
    gemm_bt<1><<<dim3(32, 17), 128, 0, stream>>>(XSb, W2, PROJ, nullptr, nullptr);
    // 5) chunked scan: 8192 waves, depth-4 register prefetch
    scan_phase1<<<2048, 256, 0, stream>>>(PROJ, XSb, alog, APROD, HFIN);
    scan_phase2<<<256, 256, 0, stream>>>(h0, APROD, HFIN, hout);
    scan_phase3<<<2048, 256, 0, stream>>>(PROJ, XSb, ZG, alog, dv, HFIN, YG);
    // 6) out = x + yg @ W_out^T
    gemm_bt<2><<<dim3(32, 16), 128, 0, stream>>>(YG, W3, out, nullptr, x);

    (void)in_sizes; (void)n_in; (void)out_size; (void)ws_size;
}